// Round 14
// baseline (947.076 us; speedup 1.0000x reference)
//
#include <hip/hip_runtime.h>
#include <hip/hip_bf16.h>
#include <stdint.h>

#define F_DIM 512
#define C_DIM 512
#define K3    1536   // 3 * F_DIM
#define NIT   36     // 72 flat K'-tiles (BK=64), 2 per iteration

typedef _Float16 f16x8 __attribute__((ext_vector_type(8)));
typedef float    f32x4 __attribute__((ext_vector_type(4)));

__device__ __forceinline__ float rho_of(int p, int sb) {
    int d = sb - 1; if (d < 1) d = 1;
    return (float)(p - 1) / (float)d;
}

// 2-way fp16 split with exact pow2 plane scaling: v ~= h + m*2^-11
__device__ __forceinline__ void split2s(float v, _Float16& h, _Float16& m) {
    h = (_Float16)v;
    float r1 = v - (float)h;          // exact
    m = (_Float16)(r1 * 2048.0f);     // scale exact, one rounding
}

// ---------------- CSR build ----------------
__global__ void k_count(const int* __restrict__ parent, int* __restrict__ counts, int n) {
    int c = blockIdx.x * 256 + threadIdx.x;
    if (c >= 1 && c < n) atomicAdd(&counts[parent[c]], 1);
}

__device__ __forceinline__ int blockScanIncl(int v, int* sm) {
    int lane = threadIdx.x & 63;
    int w = threadIdx.x >> 6;
    #pragma unroll
    for (int d = 1; d < 64; d <<= 1) {
        int t = __shfl_up(v, d, 64);
        if (lane >= d) v += t;
    }
    if (lane == 63) sm[w] = v;
    __syncthreads();
    if (threadIdx.x < 64) {
        int s = (threadIdx.x < 16) ? sm[threadIdx.x] : 0;
        #pragma unroll
        for (int d = 1; d < 16; d <<= 1) {
            int t = __shfl_up(s, d, 64);
            if (lane >= d) s += t;
        }
        if (threadIdx.x < 16) sm[threadIdx.x] = s;
    }
    __syncthreads();
    return v + (w > 0 ? sm[w - 1] : 0);
}

__global__ void k_scan1(const int* __restrict__ counts, int* __restrict__ starts,
                        int* __restrict__ bsums, int n) {
    __shared__ int sm[16];
    int i = blockIdx.x * 1024 + threadIdx.x;
    int v = (i < n) ? counts[i] : 0;
    int incl = blockScanIncl(v, sm);
    if (i < n) starts[i] = incl - v;
    if (threadIdx.x == 1023) bsums[blockIdx.x] = incl;
}

__global__ void k_scan2(int* __restrict__ bsums, int nb) {
    __shared__ int sm[16];
    int v = ((int)threadIdx.x < nb) ? bsums[threadIdx.x] : 0;
    int incl = blockScanIncl(v, sm);
    if ((int)threadIdx.x < nb) bsums[threadIdx.x] = incl - v;  // exclusive
}

__global__ void k_scan3(int* __restrict__ starts, const int* __restrict__ bsums, int n) {
    int i = blockIdx.x * 1024 + threadIdx.x;
    if (i < n) starts[i] += bsums[blockIdx.x];
}

__global__ void k_fill(const int* __restrict__ parent, const int* __restrict__ pos,
                       const int* __restrict__ starts, int* __restrict__ childlist, int n) {
    int c = blockIdx.x * 256 + threadIdx.x;
    if (c >= 1 && c < n) childlist[starts[parent[c]] + pos[c]] = c;
}

// ---------------- B concat + 2-way split:  B[j][sec*512+f], sec: 0=Wt 1=Wl 2=Wr
__global__ void k_bcat(const float* __restrict__ Wt, const float* __restrict__ Wl,
                       const float* __restrict__ Wr,
                       _Float16* __restrict__ Bh, _Float16* __restrict__ Bm) {
    int i = blockIdx.x * 256 + threadIdx.x;
    if (i >= C_DIM * K3) return;
    int j = i / K3, kk = i - j * K3;
    int sec = kk >> 9, f = kk & 511;
    const float* W = (sec == 0) ? Wt : ((sec == 1) ? Wl : Wr);
    float v = W[j * F_DIM + f];
    _Float16 h, m;
    split2s(v, h, m);
    Bh[i] = h; Bm[i] = m;
}

// ---------------- aggregation: one wave per node.
__global__ __launch_bounds__(256)
void k_agg(const float* __restrict__ x, const int* __restrict__ level,
           const int* __restrict__ pos, const int* __restrict__ sib,
           const int* __restrict__ starts, const int* __restrict__ counts,
           const int* __restrict__ childlist,
           _Float16* __restrict__ Ah, _Float16* __restrict__ Am,
           int node0, int cnt) {
    int lane = threadIdx.x & 63;
    int gw = (blockIdx.x * 256 + threadIdx.x) >> 6;
    int nW = (gridDim.x * 256) >> 6;
    for (int i = gw; i < cnt; i += nW) {
        int s = node0 + i;
        float t = 0.5f * (float)level[s];
        float u = 1.0f - t;
        float u2 = u * u;
        float s0[8], s1[8];
        #pragma unroll
        for (int j = 0; j < 8; ++j) { s0[j] = 0.f; s1[j] = 0.f; }
        {
            float r = rho_of(pos[s], sib[s]);
            const float4* xp = (const float4*)(x + (size_t)s * F_DIM) + lane * 2;
            float4 a = xp[0], b = xp[1];
            float vv[8] = {a.x, a.y, a.z, a.w, b.x, b.y, b.z, b.w};
            #pragma unroll
            for (int j = 0; j < 8; ++j) { s0[j] += vv[j]; s1[j] = fmaf(r, vv[j], s1[j]); }
        }
        int cs = starts[s], ne = counts[s];
        for (int e = 0; e < ne; ++e) {
            int c = childlist[cs + e];
            float r = rho_of(pos[c], sib[c]);
            const float4* xp = (const float4*)(x + (size_t)c * F_DIM) + lane * 2;
            float4 a = xp[0], b = xp[1];
            float vv[8] = {a.x, a.y, a.z, a.w, b.x, b.y, b.z, b.w};
            #pragma unroll
            for (int j = 0; j < 8; ++j) { s0[j] += vv[j]; s1[j] = fmaf(r, vv[j], s1[j]); }
        }
        f16x8 ph[3], pm[3];
        #pragma unroll
        for (int j = 0; j < 8; ++j) {
            float a0 = t * s0[j];
            float a1 = fmaf(-u2, s1[j], u * s0[j]);
            float a2 = u * s1[j];
            _Float16 h, m;
            split2s(a0, h, m); ph[0][j] = h; pm[0][j] = m;
            split2s(a1, h, m); ph[1][j] = h; pm[1][j] = m;
            split2s(a2, h, m); ph[2][j] = h; pm[2][j] = m;
        }
        size_t rb = (size_t)i * K3 + (size_t)(lane * 8);
        #pragma unroll
        for (int sec = 0; sec < 3; ++sec) {
            *(f16x8*)(Ah + rb + sec * 512) = ph[sec];
            *(f16x8*)(Am + rb + sec * 512) = pm[sec];
        }
    }
}

// ---------------- GEMM: out = tanh(A(M x 1536) * Bcat^T + (1+nc)*bias)
// Faithful m201 8-phase port. Flat K' = 4608 over plane-pair segments:
//   tiles [0,24): Am x Bh ; [24,48): Ah x Bm ; rescale acc *= 2^-11 (exact)
//   at tile 48 ; [48,72): Ah x Bh.   (Numerics verified in R10: 3.906e-3.)
// Geometry: BM=BN=256, BK=64; 512 thr = 8 waves (2M x 4N), wave 128x64;
// single acc bank acc[8][4] = 128 AGPR. LDS: 2-slot dbuf, slot = tile&1,
// sA/sB[2][256x64] = 128 KB.
// Schedule per iteration (2 tiles t0=2i slot0, t1 slot1), 8 phases, each:
//   { ds_read (8 if B-refresh else 4) ; 2 global_load_lds ; s_barrier ;
//     setprio(1) ; 16 MFMA ; setprio(0) ; [vmcnt at p4/p8] ; s_barrier }
// Staging plan (region-disjoint with concurrent reads, 1.5-tile lookahead):
//   p1: t1.A g1,g3   p2: t1.B g0,g1   p3: t1.B g2,g3   p4: t2.A g0,g2
//   p5: t2.A g1,g3   p6: t2.B g0,g1   p7: t2.B g2,g3   p8: t3.A g0,g2
// vmcnt(2) after p4 MFMA (t1 fully landed; t2.Ag0g2 stays in flight) and
// after p8 (t2 landed; t3.Ag0g2 in flight) — counted, never drains.
// Swizzle: R7-verified (0 conflicts): store linear, global source slot
// ^= (row&7), ds_read slot = (kk*4+lg) ^ (lane&7).
__device__ __forceinline__ f32x4 mfma16(f16x8 a, f16x8 b, f32x4 c) {
    return __builtin_amdgcn_mfma_f32_16x16x32_f16(a, b, c, 0, 0, 0);
}

#define AS1 __attribute__((address_space(1)))
#define AS3 __attribute__((address_space(3)))

__global__ __launch_bounds__(512, 2)
void k_gemm(const _Float16* __restrict__ Ah, const _Float16* __restrict__ Am,
            const _Float16* __restrict__ Bh, const _Float16* __restrict__ Bm,
            const float* __restrict__ bias, const int* __restrict__ counts,
            float* __restrict__ out, int Mreal, int row0) {
    __shared__ __align__(16) _Float16 sA[2][256 * 64];
    __shared__ __align__(16) _Float16 sB[2][256 * 64];

    // bijective XCD swizzle (m204); 2 col-tiles of an M-panel share an XCD
    int nwg = gridDim.x, bid = blockIdx.x;
    int q = nwg >> 3, r = nwg & 7;
    int xcd = bid & 7, idx = bid >> 3;
    int wg = (xcd < r ? xcd * (q + 1) : r * (q + 1) + (xcd - r) * q) + idx;
    int panel = wg >> 1, colt = wg & 1;
    int m0 = panel * 256, n0 = colt * 256;

    int tid = threadIdx.x;
    int lane = tid & 63, wid = tid >> 6;
    int wm = wid >> 2, wn = wid & 3;            // 2 x 4 waves, wave tile 128x64
    int l15 = lane & 15, lg = lane >> 4, lx = lane & 7;

    const char* gAh = (const char*)(Ah + (size_t)m0 * K3);
    const char* gAm = (const char*)(Am + (size_t)m0 * K3);
    const char* gBh = (const char*)(Bh + (size_t)n0 * K3);
    const char* gBm = (const char*)(Bm + (size_t)n0 * K3);

    // staging offsets: 2048 16B-chunks per 256x64 tile; thread owns chunks
    // {g*512 + tid}; row = c>>3, source slot inverse-swizzled.
    int sOff[4], dOff[4];
    #pragma unroll
    for (int g = 0; g < 4; ++g) {
        int c = g * 512 + tid;
        int row = c >> 3;
        int gslot = (c & 7) ^ (row & 7);
        sOff[g] = row * (K3 * 2) + (gslot << 4);
        dOff[g] = (g * 512 + wid * 64) * 8;     // wave-uniform linear dest
    }

    // flat-K' source selectors
    auto asrc = [&](int t) -> const char* {
        return (t < 24) ? (gAm + (size_t)t * 128)
             : (t < 48) ? (gAh + (size_t)(t - 24) * 128)
                        : (gAh + (size_t)(t - 48) * 128);
    };
    auto bsrc = [&](int t) -> const char* {
        return (t < 24) ? (gBh + (size_t)t * 128)
             : (t < 48) ? (gBm + (size_t)(t - 24) * 128)
                        : (gBh + (size_t)(t - 48) * 128);
    };

    f32x4 acc[8][4] = {};
    f16x8 bf[4], af[4];

#define ISSUE2(SRC, G1, G2, SLDS)                                                          \
    do {                                                                                   \
        __builtin_amdgcn_global_load_lds((const AS1 unsigned int*)((SRC) + sOff[G1]),      \
            (AS3 unsigned int*)(&(SLDS)[dOff[G1]]), 16, 0, 0);                             \
        __builtin_amdgcn_global_load_lds((const AS1 unsigned int*)((SRC) + sOff[G2]),      \
            (AS3 unsigned int*)(&(SLDS)[dOff[G2]]), 16, 0, 0);                             \
    } while (0)

#define PHASE(PA, PB, KK, GRP, READB, STAGES, WAITS)                                       \
    do {                                                                                   \
        int ko_ = (((KK) * 4 + lg) ^ lx) << 3;                                             \
        if (READB) {                                                                       \
            _Pragma("unroll")                                                              \
            for (int ni = 0; ni < 4; ++ni)                                                 \
                bf[ni] = *(const f16x8*)&(PA ## _B)[(wn * 64 + ni * 16 + l15) * 64 + ko_]; \
        }                                                                                  \
        _Pragma("unroll")                                                                  \
        for (int mi = 0; mi < 4; ++mi)                                                     \
            af[mi] = *(const f16x8*)&(PA)[(wm * 128 + (GRP) * 64 + mi * 16 + l15) * 64 + ko_]; \
        STAGES;                                                                            \
        asm volatile("s_barrier" ::: "memory");                                            \
        __builtin_amdgcn_s_setprio(1);                                                     \
        _Pragma("unroll")                                                                  \
        for (int mi = 0; mi < 4; ++mi)                                                     \
            _Pragma("unroll")                                                              \
            for (int ni = 0; ni < 4; ++ni)                                                 \
                acc[(GRP) * 4 + mi][ni] = mfma16(af[mi], bf[ni], acc[(GRP) * 4 + mi][ni]); \
        __builtin_amdgcn_s_setprio(0);                                                     \
        WAITS;                                                                             \
        asm volatile("s_barrier" ::: "memory");                                            \
    } while (0)

#define VMC(n) asm volatile("s_waitcnt vmcnt(" #n ")" ::: "memory")

    const _Float16* sA0 = sA[0]; const _Float16* sA0_B = sB[0];
    const _Float16* sA1 = sA[1]; const _Float16* sA1_B = sB[1];

    // prologue: stage tile 0 fully + tile 1 A g0,g2 (10 loads); wait to 2.
    {
        const char* A0 = asrc(0); const char* B0 = bsrc(0); const char* A1 = asrc(1);
        ISSUE2(A0, 0, 1, sA[0]); ISSUE2(A0, 2, 3, sA[0]);
        ISSUE2(B0, 0, 1, sB[0]); ISSUE2(B0, 2, 3, sB[0]);
        ISSUE2(A1, 0, 2, sA[1]);
        VMC(2);
        asm volatile("s_barrier" ::: "memory");
    }

    for (int i = 0; i < NIT; ++i) {
        bool last = (i == NIT - 1);
        int t1 = 2 * i + 1, t2 = t1 + 1, t3 = t1 + 2;
        const char* A1s = asrc(t1); const char* B1s = bsrc(t1);
        const char* A2s = last ? A1s : asrc(t2);
        const char* B2s = last ? B1s : bsrc(t2);
        const char* A3s = last ? A1s : asrc(t3);

        if (i == 24) {                     // cross-sum done -> exact 2^-11 scale
            #pragma unroll
            for (int mi = 0; mi < 8; ++mi)
                #pragma unroll
                for (int ni = 0; ni < 4; ++ni)
                    acc[mi][ni] *= (1.0f / 2048.0f);
        }

        // ---- tile t0 = 2i from slot 0 ----
        PHASE(sA0, xx, 0, 0, true,  ISSUE2(A1s, 1, 3, sA[1]), (void)0);
        PHASE(sA0, xx, 0, 1, false, ISSUE2(B1s, 0, 1, sB[1]), (void)0);
        PHASE(sA0, xx, 1, 0, true,  ISSUE2(B1s, 2, 3, sB[1]), (void)0);
        if (!last) { PHASE(sA0, xx, 1, 1, false, ISSUE2(A2s, 0, 2, sA[0]), VMC(2)); }
        else       { PHASE(sA0, xx, 1, 1, false, (void)0,                  VMC(0)); }

        // ---- tile t1 = 2i+1 from slot 1 ----
        if (!last) {
            PHASE(sA1, xx, 0, 0, true,  ISSUE2(A2s, 1, 3, sA[0]), (void)0);
            PHASE(sA1, xx, 0, 1, false, ISSUE2(B2s, 0, 1, sB[0]), (void)0);
            PHASE(sA1, xx, 1, 0, true,  ISSUE2(B2s, 2, 3, sB[0]), (void)0);
            PHASE(sA1, xx, 1, 1, false, ISSUE2(A3s, 0, 2, sA[1]), VMC(2));
        } else {
            PHASE(sA1, xx, 0, 0, true,  (void)0, (void)0);
            PHASE(sA1, xx, 0, 1, false, (void)0, (void)0);
            PHASE(sA1, xx, 1, 0, true,  (void)0, (void)0);
            PHASE(sA1, xx, 1, 1, false, (void)0, (void)0);
        }
    }
#undef PHASE
#undef ISSUE2
#undef VMC

    #pragma unroll
    for (int mi = 0; mi < 8; ++mi) {
        #pragma unroll
        for (int ni = 0; ni < 4; ++ni) {
            int colL = n0 + wn * 64 + ni * 16 + l15;
            #pragma unroll
            for (int rr = 0; rr < 4; ++rr) {
                int rowL = m0 + wm * 128 + mi * 16 + lg * 4 + rr;
                if (rowL < Mreal) {
                    int g = row0 + rowL;
                    float v = acc[mi][ni][rr]
                              + (1.0f + (float)counts[g]) * bias[colL];
                    out[(size_t)g * C_DIM + colL] = tanhf(v);
                }
            }
        }
    }
}

extern "C" void kernel_launch(void* const* d_in, const int* in_sizes, int n_in,
                              void* d_out, int out_size, void* d_ws, size_t ws_size,
                              hipStream_t stream) {
    const float* x    = (const float*)d_in[0];
    const float* Wt   = (const float*)d_in[1];
    const float* Wl   = (const float*)d_in[2];
    const float* Wr   = (const float*)d_in[3];
    const float* bias = (const float*)d_in[4];
    const int* parent = (const int*)d_in[5];
    const int* level  = (const int*)d_in[6];
    const int* pos    = (const int*)d_in[7];
    const int* sib    = (const int*)d_in[8];
    const int N = in_sizes[5];
    float* out = (float*)d_out;
    (void)n_in; (void)out_size;

    char* w = (char*)d_ws;
    size_t off = 0;
    auto alloc = [&](size_t bytes) -> void* {
        void* p = w + off;
        off += (bytes + 255) & ~(size_t)255;
        return p;
    };
    int* counts    = (int*)alloc((size_t)N * 4);
    int* starts    = (int*)alloc((size_t)N * 4);
    int* childlist = (int*)alloc((size_t)N * 4);
    int* bsums     = (int*)alloc(1024 * 4);
    _Float16* Bh   = (_Float16*)alloc((size_t)C_DIM * K3 * 2);
    _Float16* Bm   = (_Float16*)alloc((size_t)C_DIM * K3 * 2);

    size_t avail = ws_size > off ? ws_size - off : 0;
    long long Npad = ((long long)N + 255) & ~255LL;
    long long chunkM = (long long)(avail / ((size_t)K3 * 2 * 2)) & ~255LL;
    if (chunkM > Npad) chunkM = Npad;
    if (chunkM < 256) chunkM = 256;
    _Float16* Ah = (_Float16*)alloc((size_t)chunkM * K3 * 2);
    _Float16* Am = (_Float16*)alloc((size_t)chunkM * K3 * 2);

    hipMemsetAsync(counts, 0, (size_t)N * 4, stream);
    int nb256 = (N + 255) / 256;
    int nb1024 = (N + 1023) / 1024;
    k_count<<<nb256, 256, 0, stream>>>(parent, counts, N);
    k_scan1<<<nb1024, 1024, 0, stream>>>(counts, starts, bsums, N);
    k_scan2<<<1, 1024, 0, stream>>>(bsums, nb1024);
    k_scan3<<<nb1024, 1024, 0, stream>>>(starts, bsums, N);
    k_fill<<<nb256, 256, 0, stream>>>(parent, pos, starts, childlist, N);
    k_bcat<<<(C_DIM * K3 + 255) / 256, 256, 0, stream>>>(Wt, Wl, Wr, Bh, Bm);

    for (long long m0 = 0; m0 < N; m0 += chunkM) {
        int mc = (int)((N - m0 < chunkM) ? (N - m0) : chunkM);
        int mcPad = (mc + 255) & ~255;
        k_agg<<<2048, 256, 0, stream>>>(x, level, pos, sib, starts, counts, childlist,
                                        Ah, Am, (int)m0, mc);
        int ntiles = (mcPad / 256) * 2;
        k_gemm<<<ntiles, 512, 0, stream>>>(Ah, Am, Bh, Bm, bias, counts,
                                           out, mc, (int)m0);
    }
}

// Round 15
// 791.903 us; speedup vs baseline: 1.1959x; 1.1959x over previous
//
#include <hip/hip_runtime.h>
#include <hip/hip_bf16.h>
#include <stdint.h>

#define F_DIM 512
#define C_DIM 512
#define K3    1536   // 3 * F_DIM
#define NT    24     // K3 / 64

typedef _Float16 f16x8 __attribute__((ext_vector_type(8)));
typedef float    f32x4 __attribute__((ext_vector_type(4)));

__device__ __forceinline__ float rho_of(int p, int sb) {
    int d = sb - 1; if (d < 1) d = 1;
    return (float)(p - 1) / (float)d;
}

// 2-way fp16 split with exact pow2 plane scaling: v ~= h + m*2^-11
__device__ __forceinline__ void split2s(float v, _Float16& h, _Float16& m) {
    h = (_Float16)v;
    float r1 = v - (float)h;          // exact
    m = (_Float16)(r1 * 2048.0f);     // scale exact, one rounding
}

// ---------------- CSR build ----------------
__global__ void k_count(const int* __restrict__ parent, int* __restrict__ counts, int n) {
    int c = blockIdx.x * 256 + threadIdx.x;
    if (c >= 1 && c < n) atomicAdd(&counts[parent[c]], 1);
}

__device__ __forceinline__ int blockScanIncl(int v, int* sm) {
    int lane = threadIdx.x & 63;
    int w = threadIdx.x >> 6;
    #pragma unroll
    for (int d = 1; d < 64; d <<= 1) {
        int t = __shfl_up(v, d, 64);
        if (lane >= d) v += t;
    }
    if (lane == 63) sm[w] = v;
    __syncthreads();
    if (threadIdx.x < 64) {
        int s = (threadIdx.x < 16) ? sm[threadIdx.x] : 0;
        #pragma unroll
        for (int d = 1; d < 16; d <<= 1) {
            int t = __shfl_up(s, d, 64);
            if (lane >= d) s += t;
        }
        if (threadIdx.x < 16) sm[threadIdx.x] = s;
    }
    __syncthreads();
    return v + (w > 0 ? sm[w - 1] : 0);
}

__global__ void k_scan1(const int* __restrict__ counts, int* __restrict__ starts,
                        int* __restrict__ bsums, int n) {
    __shared__ int sm[16];
    int i = blockIdx.x * 1024 + threadIdx.x;
    int v = (i < n) ? counts[i] : 0;
    int incl = blockScanIncl(v, sm);
    if (i < n) starts[i] = incl - v;
    if (threadIdx.x == 1023) bsums[blockIdx.x] = incl;
}

__global__ void k_scan2(int* __restrict__ bsums, int nb) {
    __shared__ int sm[16];
    int v = ((int)threadIdx.x < nb) ? bsums[threadIdx.x] : 0;
    int incl = blockScanIncl(v, sm);
    if ((int)threadIdx.x < nb) bsums[threadIdx.x] = incl - v;  // exclusive
}

__global__ void k_scan3(int* __restrict__ starts, const int* __restrict__ bsums, int n) {
    int i = blockIdx.x * 1024 + threadIdx.x;
    if (i < n) starts[i] += bsums[blockIdx.x];
}

__global__ void k_fill(const int* __restrict__ parent, const int* __restrict__ pos,
                       const int* __restrict__ starts, int* __restrict__ childlist, int n) {
    int c = blockIdx.x * 256 + threadIdx.x;
    if (c >= 1 && c < n) childlist[starts[parent[c]] + pos[c]] = c;
}

// ---------------- B concat + 2-way split:  B[j][sec*512+f], sec: 0=Wt 1=Wl 2=Wr
__global__ void k_bcat(const float* __restrict__ Wt, const float* __restrict__ Wl,
                       const float* __restrict__ Wr,
                       _Float16* __restrict__ Bh, _Float16* __restrict__ Bm) {
    int i = blockIdx.x * 256 + threadIdx.x;
    if (i >= C_DIM * K3) return;
    int j = i / K3, kk = i - j * K3;
    int sec = kk >> 9, f = kk & 511;
    const float* W = (sec == 0) ? Wt : ((sec == 1) ? Wl : Wr);
    float v = W[j * F_DIM + f];
    _Float16 h, m;
    split2s(v, h, m);
    Bh[i] = h; Bm[i] = m;
}

// ---------------- aggregation: one wave per node.
__global__ __launch_bounds__(256)
void k_agg(const float* __restrict__ x, const int* __restrict__ level,
           const int* __restrict__ pos, const int* __restrict__ sib,
           const int* __restrict__ starts, const int* __restrict__ counts,
           const int* __restrict__ childlist,
           _Float16* __restrict__ Ah, _Float16* __restrict__ Am,
           int node0, int cnt) {
    int lane = threadIdx.x & 63;
    int gw = (blockIdx.x * 256 + threadIdx.x) >> 6;
    int nW = (gridDim.x * 256) >> 6;
    for (int i = gw; i < cnt; i += nW) {
        int s = node0 + i;
        float t = 0.5f * (float)level[s];
        float u = 1.0f - t;
        float u2 = u * u;
        float s0[8], s1[8];
        #pragma unroll
        for (int j = 0; j < 8; ++j) { s0[j] = 0.f; s1[j] = 0.f; }
        {
            float r = rho_of(pos[s], sib[s]);
            const float4* xp = (const float4*)(x + (size_t)s * F_DIM) + lane * 2;
            float4 a = xp[0], b = xp[1];
            float vv[8] = {a.x, a.y, a.z, a.w, b.x, b.y, b.z, b.w};
            #pragma unroll
            for (int j = 0; j < 8; ++j) { s0[j] += vv[j]; s1[j] = fmaf(r, vv[j], s1[j]); }
        }
        int cs = starts[s], ne = counts[s];
        for (int e = 0; e < ne; ++e) {
            int c = childlist[cs + e];
            float r = rho_of(pos[c], sib[c]);
            const float4* xp = (const float4*)(x + (size_t)c * F_DIM) + lane * 2;
            float4 a = xp[0], b = xp[1];
            float vv[8] = {a.x, a.y, a.z, a.w, b.x, b.y, b.z, b.w};
            #pragma unroll
            for (int j = 0; j < 8; ++j) { s0[j] += vv[j]; s1[j] = fmaf(r, vv[j], s1[j]); }
        }
        f16x8 ph[3], pm[3];
        #pragma unroll
        for (int j = 0; j < 8; ++j) {
            float a0 = t * s0[j];
            float a1 = fmaf(-u2, s1[j], u * s0[j]);
            float a2 = u * s1[j];
            _Float16 h, m;
            split2s(a0, h, m); ph[0][j] = h; pm[0][j] = m;
            split2s(a1, h, m); ph[1][j] = h; pm[1][j] = m;
            split2s(a2, h, m); ph[2][j] = h; pm[2][j] = m;
        }
        size_t rb = (size_t)i * K3 + (size_t)(lane * 8);
        #pragma unroll
        for (int sec = 0; sec < 3; ++sec) {
            *(f16x8*)(Ah + rb + sec * 512) = ph[sec];
            *(f16x8*)(Am + rb + sec * 512) = pm[sec];
        }
    }
}

// ---------------- GEMM: out = tanh(A(M x 1536) * Bcat^T + (1+nc)*bias)
// fp16 2-plane, 3 products (hh -> accH; hm+mh -> accR, scale 2^-11).
// R7 CHAMPION skeleton VERBATIM (635 us; best of 8 structure variants):
// 256 thr = 4 waves (2x2), wave tile 64x64, block tile 128x128, BK=64
// SINGLE-buffer, stage -> sync -> compute -> sync, 2 blocks/CU (m114
// implicit overlap), 16x16x32 core.
// ONLY change this round: COLUMN-MAJOR tile order (colt = wg/npanel).
// With m204 XCD chunking each XCD works down one column: its 786KB
// B-strip stays L2-resident; A panels stream HBM->L2->L3 once and the
// 3 later col-group re-uses hit L3 (chunk 77MB << 256MB). Row-major
// order put 1 A-panel + 4 B-strips (~3.9MB) in a 4MB L2 -> thrash,
// measured 5.7x A over-fetch (FETCH 437MB vs ~90MB min) -> staging
// loads missed to HBM (~900cyc) at both barriers.
// LDS XOR swizzle (rule #21): linear LDS dest via global_load_lds,
// INVERSE-swizzled global source (slot^(row&7)), swizzled ds_read.
__device__ __forceinline__ f32x4 mfma16(f16x8 a, f16x8 b, f32x4 c) {
    return __builtin_amdgcn_mfma_f32_16x16x32_f16(a, b, c, 0, 0, 0);
}

__device__ __forceinline__ void stageTile(const char* gbase, _Float16* lds) {
    int tid = threadIdx.x;
    int wid = tid >> 6;
    #pragma unroll
    for (int rnd = 0; rnd < 4; ++rnd) {
        int c = rnd * 256 + tid;          // 16B chunk id within [128 rows][8 slots]
        int row = c >> 3;
        int gslot = (c & 7) ^ (row & 7);  // inverse swizzle on the SOURCE
        const void* gp = gbase + (size_t)row * (K3 * 2) + ((size_t)gslot << 4);
        _Float16* lp = lds + (size_t)(rnd * 256 + wid * 64) * 8;  // wave-uniform base
        __builtin_amdgcn_global_load_lds(
            (const __attribute__((address_space(1))) unsigned int*)gp,
            (__attribute__((address_space(3))) unsigned int*)lp, 16, 0, 0);
    }
}

__global__ __launch_bounds__(256, 2)
void k_gemm(const _Float16* __restrict__ Ah, const _Float16* __restrict__ Am,
            const _Float16* __restrict__ Bh, const _Float16* __restrict__ Bm,
            const float* __restrict__ bias, const int* __restrict__ counts,
            float* __restrict__ out, int Mreal, int row0) {
    __shared__ __align__(16) _Float16 sAh[128 * 64];
    __shared__ __align__(16) _Float16 sAm[128 * 64];
    __shared__ __align__(16) _Float16 sBh[128 * 64];
    __shared__ __align__(16) _Float16 sBm[128 * 64];

    // bijective XCD swizzle (m204) + COLUMN-MAJOR tile order:
    // consecutive wg on one XCD share the same B-strip (L2-resident).
    int nwg = gridDim.x, bid = blockIdx.x;
    int q = nwg >> 3, r = nwg & 7;
    int xcd = bid & 7, idx = bid >> 3;
    int wg = (xcd < r ? xcd * (q + 1) : r * (q + 1) + (xcd - r) * q) + idx;
    int npanel = nwg >> 2;                    // tiles per column (M/128)
    int colt = wg / npanel;                   // 0..3
    int panel = wg - colt * npanel;
    int m0 = panel * 128, n0 = colt * 128;

    int lane = threadIdx.x & 63, wid = threadIdx.x >> 6;
    int wm = wid >> 1, wn = wid & 1;
    int l15 = lane & 15, lg = lane >> 4, lx = lane & 7;

    const char* gAh = (const char*)(Ah + (size_t)m0 * K3);
    const char* gAm = (const char*)(Am + (size_t)m0 * K3);
    const char* gBh = (const char*)(Bh + (size_t)n0 * K3);
    const char* gBm = (const char*)(Bm + (size_t)n0 * K3);

    f32x4 accH[4][4] = {};
    f32x4 accR[4][4] = {};

    int koff0 = ((((0 << 2) + lg) ^ lx) << 3);
    int koff1 = ((((1 << 2) + lg) ^ lx) << 3);

    for (int t = 0; t < NT; ++t) {
        size_t kb = (size_t)t * 128;     // 64 elems * 2B along K
        stageTile(gAh + kb, sAh); stageTile(gAm + kb, sAm);
        stageTile(gBh + kb, sBh); stageTile(gBm + kb, sBm);
        __syncthreads();                 // drain hidden by co-resident block

        #pragma unroll
        for (int kc = 0; kc < 2; ++kc) {
            int ko = kc ? koff1 : koff0;
            f16x8 ah[4], am[4], bh[4], bm[4];
            #pragma unroll
            for (int ni = 0; ni < 4; ++ni) {
                int co = (wn * 64 + ni * 16 + l15) * 64 + ko;
                bh[ni] = *(const f16x8*)&sBh[co];
                bm[ni] = *(const f16x8*)&sBm[co];
            }
            #pragma unroll
            for (int mi = 0; mi < 4; ++mi) {
                int ro = (wm * 64 + mi * 16 + l15) * 64 + ko;
                ah[mi] = *(const f16x8*)&sAh[ro];
                am[mi] = *(const f16x8*)&sAm[ro];
            }
            #pragma unroll
            for (int mi = 0; mi < 4; ++mi) {
                #pragma unroll
                for (int ni = 0; ni < 4; ++ni) {
                    accH[mi][ni] = mfma16(ah[mi], bh[ni], accH[mi][ni]);
                    accR[mi][ni] = mfma16(ah[mi], bm[ni], accR[mi][ni]);
                    accR[mi][ni] = mfma16(am[mi], bh[ni], accR[mi][ni]);
                }
            }
        }
        __syncthreads();                 // reads done -> safe to overwrite
    }

    const float S1 = 1.0f / 2048.0f;        // 2^-11

    #pragma unroll
    for (int mi = 0; mi < 4; ++mi) {
        #pragma unroll
        for (int ni = 0; ni < 4; ++ni) {
            int colL = n0 + wn * 64 + ni * 16 + l15;
            #pragma unroll
            for (int rr = 0; rr < 4; ++rr) {
                int rowL = m0 + wm * 64 + mi * 16 + lg * 4 + rr;
                if (rowL < Mreal) {
                    int g = row0 + rowL;
                    float v = accH[mi][ni][rr]
                              + accR[mi][ni][rr] * S1
                              + (1.0f + (float)counts[g]) * bias[colL];
                    out[(size_t)g * C_DIM + colL] = tanhf(v);
                }
            }
        }
    }
}

extern "C" void kernel_launch(void* const* d_in, const int* in_sizes, int n_in,
                              void* d_out, int out_size, void* d_ws, size_t ws_size,
                              hipStream_t stream) {
    const float* x    = (const float*)d_in[0];
    const float* Wt   = (const float*)d_in[1];
    const float* Wl   = (const float*)d_in[2];
    const float* Wr   = (const float*)d_in[3];
    const float* bias = (const float*)d_in[4];
    const int* parent = (const int*)d_in[5];
    const int* level  = (const int*)d_in[6];
    const int* pos    = (const int*)d_in[7];
    const int* sib    = (const int*)d_in[8];
    const int N = in_sizes[5];
    float* out = (float*)d_out;
    (void)n_in; (void)out_size;

    char* w = (char*)d_ws;
    size_t off = 0;
    auto alloc = [&](size_t bytes) -> void* {
        void* p = w + off;
        off += (bytes + 255) & ~(size_t)255;
        return p;
    };
    int* counts    = (int*)alloc((size_t)N * 4);
    int* starts    = (int*)alloc((size_t)N * 4);
    int* childlist = (int*)alloc((size_t)N * 4);
    int* bsums     = (int*)alloc(1024 * 4);
    _Float16* Bh   = (_Float16*)alloc((size_t)C_DIM * K3 * 2);
    _Float16* Bm   = (_Float16*)alloc((size_t)C_DIM * K3 * 2);

    size_t avail = ws_size > off ? ws_size - off : 0;
    long long Npad = ((long long)N + 127) & ~127LL;
    long long chunkM = (long long)(avail / ((size_t)K3 * 2 * 2)) & ~127LL;
    if (chunkM > Npad) chunkM = Npad;
    if (chunkM < 128) chunkM = 128;
    _Float16* Ah = (_Float16*)alloc((size_t)chunkM * K3 * 2);
    _Float16* Am = (_Float16*)alloc((size_t)chunkM * K3 * 2);

    hipMemsetAsync(counts, 0, (size_t)N * 4, stream);
    int nb256 = (N + 255) / 256;
    int nb1024 = (N + 1023) / 1024;
    k_count<<<nb256, 256, 0, stream>>>(parent, counts, N);
    k_scan1<<<nb1024, 1024, 0, stream>>>(counts, starts, bsums, N);
    k_scan2<<<1, 1024, 0, stream>>>(bsums, nb1024);
    k_scan3<<<nb1024, 1024, 0, stream>>>(starts, bsums, N);
    k_fill<<<nb256, 256, 0, stream>>>(parent, pos, starts, childlist, N);
    k_bcat<<<(C_DIM * K3 + 255) / 256, 256, 0, stream>>>(Wt, Wl, Wr, Bh, Bm);

    for (long long m0 = 0; m0 < N; m0 += chunkM) {
        int mc = (int)((N - m0 < chunkM) ? (N - m0) : chunkM);
        int mcPad = (mc + 127) & ~127;
        k_agg<<<2048, 256, 0, stream>>>(x, level, pos, sib, starts, counts, childlist,
                                        Ah, Am, (int)m0, mc);
        int ntiles = (mcPad / 128) * 4;
        k_gemm<<<ntiles, 256, 0, stream>>>(Ah, Am, Bh, Bm, bias, counts,
                                           out, mc, (int)m0);
    }
}